// Round 6
// baseline (1270.245 us; speedup 1.0000x reference)
//
#include <hip/hip_runtime.h>

// FHETinyGPT forward: emb-gather -> q/k/v proj -> QK^T+poly-act -> PV -> wo -> logits.
// Small/medium matmuls: m97-structure gemm_bt (128x128, BK=32, 4 waves).
// Logits GEMM: gemm_bt_256x128 — BM=256,BN=128,BK=32, 8 waves (4Mx2N), per-wave
// 64x64, LDS = 3 buffers x 24KB = 72KB -> 2 blocks/CU (epilogue/prologue of one
// block overlaps the other's K-loop). Depth-2 prefetch, vmcnt(3) counted wait,
// ONE barrier per K-tile. R6 fixes R5's (bi+2)%3 rotation bug (staged into the
// live buffer) and adds the R4-verified LDS swizzle (o ^= ((o>>7)&3)<<4 within
// each 1KB subtile, applied to BOTH staging source and fragment reads ->
// SQ_LDS_BANK_CONFLICT == 0 measured in R4 with identical subtile geometry).

typedef __bf16 bf16_t;
typedef __bf16 bf16x8 __attribute__((ext_vector_type(8)));
typedef __bf16 bf16x4 __attribute__((ext_vector_type(4)));
typedef float  f32x4  __attribute__((ext_vector_type(4)));

#define VOCAB 32000
#define DIM   1024
#define BATCH 4
#define SEQ   2048
#define BT    (BATCH*SEQ)   // 8192

__device__ __forceinline__ void gload_lds16(const void* g, void* l) {
    __builtin_amdgcn_global_load_lds(
        (const __attribute__((address_space(1))) void*)g,
        (__attribute__((address_space(3))) void*)l,
        16, 0, 0);
}

// ---------------- weight cast f32 -> bf16 ------------------------------------------
__global__ void cast_f32_to_bf16(const float* __restrict__ in, bf16_t* __restrict__ out, int n4) {
    int i = blockIdx.x * blockDim.x + threadIdx.x;
    if (i < n4) {
        float4 v = ((const float4*)in)[i];
        bf16x4 o;
        o.x = (bf16_t)v.x; o.y = (bf16_t)v.y; o.z = (bf16_t)v.z; o.w = (bf16_t)v.w;
        ((bf16x4*)out)[i] = o;
    }
}

// ---------------- h = emb_w[x] * 0.01 -> bf16 [BT, DIM] ----------------------------
__global__ void embed_gather(const int* __restrict__ x, const float* __restrict__ emb,
                             bf16_t* __restrict__ h) {
    const int tok = blockIdx.x;
    const int row = x[tok];
    const float4* src = (const float4*)(emb + (long)row * DIM);
    bf16x4* dst = (bf16x4*)(h + (long)tok * DIM);
    int j = threadIdx.x;
    float4 v = src[j];
    bf16x4 o;
    o.x = (bf16_t)(v.x * 0.01f); o.y = (bf16_t)(v.y * 0.01f);
    o.z = (bf16_t)(v.z * 0.01f); o.w = (bf16_t)(v.w * 0.01f);
    dst[j] = o;
}

// ---------------- gemm_bt (m97-structure, for the small/medium matmuls) ------------
template<int ACT, typename CT>
__global__ __launch_bounds__(256) void gemm_bt(
    const bf16_t* __restrict__ A, const bf16_t* __restrict__ B, CT* __restrict__ C,
    int M, int N, int K, long sA, long sB, long sC, float scale)
{
    __shared__ __align__(16) bf16_t lsA[128 * 32];
    __shared__ __align__(16) bf16_t lsB[128 * 32];

    const int bz = blockIdx.z;
    A += (long)bz * sA;  B += (long)bz * sB;  C += (long)bz * sC;

    const int tm = blockIdx.y, tn = blockIdx.x;
    const int t = threadIdx.x;
    const int lane = t & 63, wave = t >> 6;
    const int wm = (wave >> 1) * 64;
    const int wn = (wave & 1) * 64;

    const int srow = t >> 2;
    const int scol = (t & 3) * 8;
    const bf16_t* gA = A + (long)(tm * 128 + srow) * K + scol;
    const bf16_t* gB = B + (long)(tn * 128 + srow) * K + scol;
    bf16_t* lA = &lsA[srow * 32 + scol];
    bf16_t* lB = &lsB[srow * 32 + scol];

    f32x4 acc[4][4];
#pragma unroll
    for (int i = 0; i < 4; ++i)
#pragma unroll
        for (int j = 0; j < 4; ++j)
            acc[i][j] = (f32x4){0.f, 0.f, 0.f, 0.f};

    const int arow = lane & 15;
    const int acol = (lane >> 4) * 8;

    for (int k0 = 0; k0 < K; k0 += 32) {
        __syncthreads();
        gload_lds16(gA + k0,                lA);
        gload_lds16(gA + k0 + 64 * (long)K, lA + 64 * 32);
        gload_lds16(gB + k0,                lB);
        gload_lds16(gB + k0 + 64 * (long)K, lB + 64 * 32);
        __syncthreads();

        bf16x8 af[4], bfr[4];
#pragma unroll
        for (int i = 0; i < 4; ++i) {
            af[i]  = *(const bf16x8*)&lsA[(wm + i * 16 + arow) * 32 + acol];
            bfr[i] = *(const bf16x8*)&lsB[(wn + i * 16 + arow) * 32 + acol];
        }
#pragma unroll
        for (int i = 0; i < 4; ++i)
#pragma unroll
            for (int j = 0; j < 4; ++j)
                acc[i][j] = __builtin_amdgcn_mfma_f32_16x16x32_bf16(af[i], bfr[j], acc[i][j], 0, 0, 0);
    }

    const int crow0 = tm * 128 + wm + (lane >> 4) * 4;
    const int ccol0 = tn * 128 + wn + (lane & 15);
#pragma unroll
    for (int i = 0; i < 4; ++i)
#pragma unroll
        for (int j = 0; j < 4; ++j)
#pragma unroll
            for (int r = 0; r < 4; ++r) {
                float s = acc[i][j][r] * scale;
                if (ACT) s = s * s * 0.1f + s * 0.1f;
                C[(long)(crow0 + i * 16 + r) * N + (ccol0 + j * 16)] = (CT)s;
            }
}

// ---------------- gemm_bt_256x128: C[M,N] = scale * A[M,K] @ B[N,K]^T, f32 out -----
// Requires: M == 8192 (32 M-tiles, band swizzle), N % 128 == 0, K % 64 == 0.
// Grid: 1-D (M/256)*(N/128) blocks x 512 threads.
__global__ __launch_bounds__(512, 4) void gemm_bt_256x128(
    const bf16_t* __restrict__ A, const bf16_t* __restrict__ B, float* __restrict__ C,
    int N, int K, float scale)
{
    __shared__ __align__(16) char sm[3 * 24576];   // 3 bufs x (A 16KB + B 8KB)

    // band swizzle: XCD k owns tm in [4k,4k+4); tm-inner-4, tn-outer.
    const int lin = blockIdx.x;
    const int xcd = lin & 7, jj = lin >> 3;
    const int tm = xcd * 4 + (jj & 3);
    const int tn = jj >> 2;
    const long trow0 = (long)tm * 256, tcol0 = (long)tn * 128;

    const int tid  = threadIdx.x;
    const int lane = tid & 63;
    const int wave = tid >> 6;
    const int wm = wave >> 1;            // 0..3 (M quarter owner pieces; see epilogue)
    const int wn = wave & 1;             // 0..1 (N half)
    // fragment read: logical (row = lane&15, 16B-slot = lane>>4) within a 1KB
    // subtile; physical slot = logical ^ ((row>>1)&3)  (R4-verified, 0 conflicts)
    const int rb = (lane & 15) * 64 +
                   (((lane >> 4) * 16) ^ ((((lane & 15) >> 1) & 3) << 4));

    // staging: thread t writes LDS bytes [t*16, t*16+16) of an 8KB half (linear
    // dest for global_load_lds); the global SOURCE is pre-swizzled with the same
    // involution: logical slot of physical offset o is o ^ (((o>>7)&3)<<4).
    const int o0 = tid * 16;
    const int ol = o0 ^ (((o0 >> 7) & 3) << 4);
    const int sr   = ol >> 6;            // source row within 128-row half
    const int scol = (ol & 63) >> 1;     // source col element within BK=32
    const bf16_t* Abase = A + trow0 * K;
    const bf16_t* Bbase = B + tcol0 * K;

    // stage K-tile kt (A 16KB = 2 calls, B 8KB = 1 call) into buffer bi
#define STAGE_A(kt, bi) do {                                                          \
    char* la_ = sm + (bi) * 24576;                                                    \
    gload_lds16(Abase + (long)sr * K         + ((kt) * 32 + scol), la_ + o0);         \
    gload_lds16(Abase + (long)(128 + sr) * K + ((kt) * 32 + scol), la_ + 8192 + o0);  \
} while (0)
#define STAGE_B(kt, bi) do {                                                          \
    char* lb_ = sm + (bi) * 24576 + 16384;                                            \
    gload_lds16(Bbase + (long)sr * K + ((kt) * 32 + scol), lb_ + o0);                 \
} while (0)

    f32x4 acc[4][4];
#pragma unroll
    for (int i = 0; i < 4; ++i)
#pragma unroll
        for (int j = 0; j < 4; ++j)
            acc[i][j] = (f32x4){0.f, 0.f, 0.f, 0.f};

    // phase nh: read 4 A-frags (wave's rows) + 2 B-frags (B-half nh); 8 MFMA.
    // A rows for acc i: half (i>>1) (8KB), row-in-half wm*32 + (i&1)*16.
    // B rows for (nh,j): nh*64 + wn*32 + j*16.
#define PHASE(nh, bi, ...) do {                                                       \
    const char* ba_ = sm + (bi) * 24576;                                              \
    bf16x8 af_[4], bv_[2];                                                            \
    _Pragma("unroll")                                                                 \
    for (int i_ = 0; i_ < 4; ++i_)                                                    \
        af_[i_] = *(const bf16x8*)(ba_ + (i_ >> 1) * 8192 +                           \
                                   (wm * 2 + (i_ & 1)) * 1024 + rb);                  \
    _Pragma("unroll")                                                                 \
    for (int j_ = 0; j_ < 2; ++j_)                                                    \
        bv_[j_] = *(const bf16x8*)(ba_ + 16384 + (nh) * 4096 +                        \
                                   (wn * 2 + j_) * 1024 + rb);                        \
    __VA_ARGS__;                                                                      \
    __builtin_amdgcn_s_setprio(1);                                                    \
    _Pragma("unroll")                                                                 \
    for (int i_ = 0; i_ < 4; ++i_)                                                    \
        _Pragma("unroll")                                                             \
        for (int j_ = 0; j_ < 2; ++j_)                                                \
            acc[i_][(nh) * 2 + j_] = __builtin_amdgcn_mfma_f32_16x16x32_bf16(         \
                af_[i_], bv_[j_], acc[i_][(nh) * 2 + j_], 0, 0, 0);                   \
    __builtin_amdgcn_s_setprio(0);                                                    \
} while (0)

    // prologue: tiles 0 and 1 (3 loads each); vmcnt(3) => tile 0 landed.
    STAGE_A(0, 0); STAGE_B(0, 0);
    STAGE_A(1, 1); STAGE_B(1, 1);
    asm volatile("s_waitcnt vmcnt(3)" ::: "memory");
    __builtin_amdgcn_s_barrier();

    const int NT = K / 32;
    int bi = 0;
    for (int t = 0; t < NT; ++t) {
        // stage target = (bi+2)%3: last read at tile t-1, sealed by its barrier.
        // (R5 BUG was here: wrong modulo mapping staged into the LIVE buffer.)
        const int bn = (bi + 2 >= 3) ? bi - 1 : bi + 2;
        const bool pf = (t + 2 < NT);
        // phase 0 (B-half 0): stage A(t+2) alongside
        if (pf) PHASE(0, bi, STAGE_A(t + 2, bn));
        else    PHASE(0, bi, );
        // phase 1 (B-half 1): stage B(t+2)
        if (pf) PHASE(1, bi, STAGE_B(t + 2, bn));
        else    PHASE(1, bi, );
        // tile boundary: vmcnt(3) leaves only this tile's 3 staged loads
        // outstanding => tile t+1 fully landed; barrier seals this tile's reads.
        if (pf) { asm volatile("s_waitcnt vmcnt(3)" ::: "memory"); }
        else    { asm volatile("s_waitcnt vmcnt(0)" ::: "memory"); }
        __builtin_amdgcn_s_barrier();
        bi = (bi == 2) ? 0 : bi + 1;
    }

    // epilogue: C/D layout col=lane&15, row=(lane>>4)*4+reg
    const int erow = (lane >> 4) * 4;
    const int ecol = lane & 15;
#pragma unroll
    for (int i = 0; i < 4; ++i)
#pragma unroll
        for (int j = 0; j < 4; ++j)
#pragma unroll
            for (int r = 0; r < 4; ++r) {
                long row = trow0 + (i >> 1) * 128 + wm * 32 + (i & 1) * 16 + erow + r;
                long col = tcol0 + (j >> 1) * 64 + wn * 32 + (j & 1) * 16 + ecol;
                C[row * N + col] = acc[i][j][r] * scale;
            }
#undef PHASE
#undef STAGE_A
#undef STAGE_B
}

// -----------------------------------------------------------------------------------
extern "C" void kernel_launch(void* const* d_in, const int* in_sizes, int n_in,
                              void* d_out, int out_size, void* d_ws, size_t ws_size,
                              hipStream_t stream) {
    const int*   x    = (const int*)d_in[0];
    const float* emb  = (const float*)d_in[1];
    const float* wq   = (const float*)d_in[2];
    const float* wk   = (const float*)d_in[3];
    const float* wv   = (const float*)d_in[4];
    const float* wo   = (const float*)d_in[5];
    const float* wout = (const float*)d_in[6];
    float* logits = (float*)d_out;

    char* ws = (char*)d_ws;
    size_t off = 0;
    auto alloc = [&](size_t bytes) {
        char* p = ws + off;
        off += (bytes + 255) & ~(size_t)255;
        return p;
    };
    bf16_t* hb    = (bf16_t*)alloc((size_t)BT * DIM * 2);
    bf16_t* qb    = (bf16_t*)alloc((size_t)BT * DIM * 2);
    bf16_t* kb    = (bf16_t*)alloc((size_t)BT * DIM * 2);
    bf16_t* vtb   = (bf16_t*)alloc((size_t)BATCH * DIM * SEQ * 2);
    bf16_t* attnb = (bf16_t*)alloc((size_t)BATCH * SEQ * SEQ * 2);
    bf16_t* o1b   = (bf16_t*)alloc((size_t)BT * DIM * 2);
    bf16_t* o2b   = (bf16_t*)alloc((size_t)BT * DIM * 2);
    bf16_t* wqb   = (bf16_t*)alloc((size_t)DIM * DIM * 2);
    bf16_t* wkb   = (bf16_t*)alloc((size_t)DIM * DIM * 2);
    bf16_t* wvb   = (bf16_t*)alloc((size_t)DIM * DIM * 2);
    bf16_t* wob   = (bf16_t*)alloc((size_t)DIM * DIM * 2);
    bf16_t* woutb = (bf16_t*)alloc((size_t)VOCAB * DIM * 2);

    {
        int n4 = DIM * DIM / 4;
        cast_f32_to_bf16<<<n4 / 256, 256, 0, stream>>>(wq, wqb, n4);
        cast_f32_to_bf16<<<n4 / 256, 256, 0, stream>>>(wk, wkb, n4);
        cast_f32_to_bf16<<<n4 / 256, 256, 0, stream>>>(wv, wvb, n4);
        cast_f32_to_bf16<<<n4 / 256, 256, 0, stream>>>(wo, wob, n4);
        int n4o = VOCAB * DIM / 4;
        cast_f32_to_bf16<<<n4o / 256, 256, 0, stream>>>(wout, woutb, n4o);
    }

    embed_gather<<<BT, 256, 0, stream>>>(x, emb, hb);

    dim3 blk(256);
    gemm_bt<0, bf16_t><<<dim3(DIM / 128, BT / 128, 1), blk, 0, stream>>>(
        hb, wqb, qb, BT, DIM, DIM, 0, 0, 0, 0.01f);
    gemm_bt<0, bf16_t><<<dim3(DIM / 128, BT / 128, 1), blk, 0, stream>>>(
        hb, wkb, kb, BT, DIM, DIM, 0, 0, 0, 0.01f);
    gemm_bt<0, bf16_t><<<dim3(SEQ / 128, DIM / 128, BATCH), blk, 0, stream>>>(
        wvb, hb, vtb, DIM, SEQ, DIM, 0, (long)SEQ * DIM, (long)DIM * SEQ, 0.1f);
    gemm_bt<1, bf16_t><<<dim3(SEQ / 128, SEQ / 128, BATCH), blk, 0, stream>>>(
        qb, kb, attnb, SEQ, SEQ, DIM,
        (long)SEQ * DIM, (long)SEQ * DIM, (long)SEQ * SEQ, 0.01f);
    gemm_bt<0, bf16_t><<<dim3(DIM / 128, SEQ / 128, BATCH), blk, 0, stream>>>(
        attnb, vtb, o1b, SEQ, DIM, SEQ,
        (long)SEQ * SEQ, (long)DIM * SEQ, (long)SEQ * DIM, 0.01f);
    gemm_bt<0, bf16_t><<<dim3(DIM / 128, BT / 128, 1), blk, 0, stream>>>(
        o1b, wob, o2b, BT, DIM, DIM, 0, 0, 0, 0.1f);

    // logits: 256x128 tiles, 3-buffer pipeline; grid = 32 * 250 = 8000 blocks
    gemm_bt_256x128<<<(BT / 256) * (VOCAB / 128), 512, 0, stream>>>(
        o2b, woutb, logits, VOCAB, DIM, 1.0f);
}

// Round 7
// 968.083 us; speedup vs baseline: 1.3121x; 1.3121x over previous
//
#include <hip/hip_runtime.h>

// FHETinyGPT forward: emb-gather -> q/k/v proj -> QK^T+poly-act -> PV -> wo -> logits.
// Small/medium matmuls: m97-structure gemm_bt (128x128, BK=32, 4 waves).
// Logits GEMM: 256x256 8-wave pipelined kernel (R4 skeleton) with R7 phase
// restructure: 0.375 ds_read_b128 per MFMA (was 0.75 -> LDS-BW capped at ~38%
// MfmaUtil; R4=33%, R6=24% both fit that model; m201's 62% needs 0.375).
// Per K-step(32): P_LO reads B[0..3]+A-h0[0..3] (8 reads) -> 16 MFMA rows 0-3;
// P_HI reads A-h1[0..3] (4 reads), reuses B regs -> 16 MFMA rows 4-7.
// Staging/swizzle/vmcnt(4) cadence identical to R4 (verified correct):
//   P0 stages t+1 h1 (idle buf); P3 stages t+2 h0 (current buf; A-h0/B last
//   read in P2, sealed by P2's barrier); tile-end vmcnt(4) => t+1 landed.

typedef __bf16 bf16_t;
typedef __bf16 bf16x8 __attribute__((ext_vector_type(8)));
typedef __bf16 bf16x4 __attribute__((ext_vector_type(4)));
typedef float  f32x4  __attribute__((ext_vector_type(4)));

#define VOCAB 32000
#define DIM   1024
#define BATCH 4
#define SEQ   2048
#define BT    (BATCH*SEQ)   // 8192

__device__ __forceinline__ void gload_lds16(const void* g, void* l) {
    __builtin_amdgcn_global_load_lds(
        (const __attribute__((address_space(1))) void*)g,
        (__attribute__((address_space(3))) void*)l,
        16, 0, 0);
}

// ---------------- weight cast f32 -> bf16 ------------------------------------------
__global__ void cast_f32_to_bf16(const float* __restrict__ in, bf16_t* __restrict__ out, int n4) {
    int i = blockIdx.x * blockDim.x + threadIdx.x;
    if (i < n4) {
        float4 v = ((const float4*)in)[i];
        bf16x4 o;
        o.x = (bf16_t)v.x; o.y = (bf16_t)v.y; o.z = (bf16_t)v.z; o.w = (bf16_t)v.w;
        ((bf16x4*)out)[i] = o;
    }
}

// ---------------- h = emb_w[x] * 0.01 -> bf16 [BT, DIM] ----------------------------
__global__ void embed_gather(const int* __restrict__ x, const float* __restrict__ emb,
                             bf16_t* __restrict__ h) {
    const int tok = blockIdx.x;
    const int row = x[tok];
    const float4* src = (const float4*)(emb + (long)row * DIM);
    bf16x4* dst = (bf16x4*)(h + (long)tok * DIM);
    int j = threadIdx.x;
    float4 v = src[j];
    bf16x4 o;
    o.x = (bf16_t)(v.x * 0.01f); o.y = (bf16_t)(v.y * 0.01f);
    o.z = (bf16_t)(v.z * 0.01f); o.w = (bf16_t)(v.w * 0.01f);
    dst[j] = o;
}

// ---------------- gemm_bt (m97-structure, for the small/medium matmuls) ------------
template<int ACT, typename CT>
__global__ __launch_bounds__(256) void gemm_bt(
    const bf16_t* __restrict__ A, const bf16_t* __restrict__ B, CT* __restrict__ C,
    int M, int N, int K, long sA, long sB, long sC, float scale)
{
    __shared__ __align__(16) bf16_t lsA[128 * 32];
    __shared__ __align__(16) bf16_t lsB[128 * 32];

    const int bz = blockIdx.z;
    A += (long)bz * sA;  B += (long)bz * sB;  C += (long)bz * sC;

    const int tm = blockIdx.y, tn = blockIdx.x;
    const int t = threadIdx.x;
    const int lane = t & 63, wave = t >> 6;
    const int wm = (wave >> 1) * 64;
    const int wn = (wave & 1) * 64;

    const int srow = t >> 2;
    const int scol = (t & 3) * 8;
    const bf16_t* gA = A + (long)(tm * 128 + srow) * K + scol;
    const bf16_t* gB = B + (long)(tn * 128 + srow) * K + scol;
    bf16_t* lA = &lsA[srow * 32 + scol];
    bf16_t* lB = &lsB[srow * 32 + scol];

    f32x4 acc[4][4];
#pragma unroll
    for (int i = 0; i < 4; ++i)
#pragma unroll
        for (int j = 0; j < 4; ++j)
            acc[i][j] = (f32x4){0.f, 0.f, 0.f, 0.f};

    const int arow = lane & 15;
    const int acol = (lane >> 4) * 8;

    for (int k0 = 0; k0 < K; k0 += 32) {
        __syncthreads();
        gload_lds16(gA + k0,                lA);
        gload_lds16(gA + k0 + 64 * (long)K, lA + 64 * 32);
        gload_lds16(gB + k0,                lB);
        gload_lds16(gB + k0 + 64 * (long)K, lB + 64 * 32);
        __syncthreads();

        bf16x8 af[4], bfr[4];
#pragma unroll
        for (int i = 0; i < 4; ++i) {
            af[i]  = *(const bf16x8*)&lsA[(wm + i * 16 + arow) * 32 + acol];
            bfr[i] = *(const bf16x8*)&lsB[(wn + i * 16 + arow) * 32 + acol];
        }
#pragma unroll
        for (int i = 0; i < 4; ++i)
#pragma unroll
            for (int j = 0; j < 4; ++j)
                acc[i][j] = __builtin_amdgcn_mfma_f32_16x16x32_bf16(af[i], bfr[j], acc[i][j], 0, 0, 0);
    }

    const int crow0 = tm * 128 + wm + (lane >> 4) * 4;
    const int ccol0 = tn * 128 + wn + (lane & 15);
#pragma unroll
    for (int i = 0; i < 4; ++i)
#pragma unroll
        for (int j = 0; j < 4; ++j)
#pragma unroll
            for (int r = 0; r < 4; ++r) {
                float s = acc[i][j][r] * scale;
                if (ACT) s = s * s * 0.1f + s * 0.1f;
                C[(long)(crow0 + i * 16 + r) * N + (ccol0 + j * 16)] = (CT)s;
            }
}

// ---------------- 256x256 pipelined GEMM: C[M,N] = scale * A[M,K] @ B[N,K]^T -------
// Requires: M == 8192 (32 M-tiles, band swizzle), N % 256 == 0, K % 128 == 0.
// Grid: 1-D, (M/256)*(N/256) blocks of 512 threads.
__global__ __launch_bounds__(512, 2) void gemm_bt_256(
    const bf16_t* __restrict__ A, const bf16_t* __restrict__ B, float* __restrict__ C,
    int N, int K, float scale)
{
    __shared__ __align__(16) char smem[131072];   // 2buf x (A 32KB + B 32KB)
    char* const sm = smem;

    // band swizzle: XCD k owns tm in [4k, 4k+4); tm-inner-4, tn-outer.
    const int lin = blockIdx.x;
    const int xcd = lin & 7, jj = lin >> 3;
    const int tm = xcd * 4 + (jj & 3);
    const int tn = jj >> 2;
    const long trow0 = (long)tm * 256, tcol0 = (long)tn * 256;

    const int tid  = threadIdx.x;
    const int lane = tid & 63;
    const int wave = tid >> 6;
    const int wm = wave >> 2;            // 0..1  (M sub-band within each 128-half)
    const int wn = wave & 3;             // 0..3
    const int lr = lane & 15;
    const int ko2 = (lane >> 4) * 16;    // byte offset of this lane's 16B k-chunk
    // swizzled per-thread byte offset within a 1KB subtile (involution on bits 4-5)
    const int rbase = lr * 64 + (ko2 ^ (((lr >> 1) & 3) << 4));

    // staging decode (R4-verified): physical slot o holds logical slot sigma(o)
    const int o0 = tid * 16, o1 = 8192 + tid * 16;
    int sr0, sc0, sr1, sc1;
    {
        int ol = o0 ^ (((o0 >> 7) & 3) << 4);
        sr0 = ((ol >> 10) >> 1) * 16 + ((ol >> 6) & 15);
        sc0 = ((ol >> 10) & 1) * 32 + ((ol & 63) >> 1);
        ol = o1 ^ (((o1 >> 7) & 3) << 4);
        sr1 = ((ol >> 10) >> 1) * 16 + ((ol >> 6) & 15);
        sc1 = ((ol >> 10) & 1) * 32 + ((ol & 63) >> 1);
    }

    const bf16_t* Abase = A + trow0 * K;
    const bf16_t* Bbase = B + tcol0 * K;

    // stage one half-tile (128 rows x 64 cols) of K-tile kt into LDS half at ldsh
#define STAGE_HT(gbase, kt, half, ldsh) do {                                          \
    gload_lds16((gbase) + (long)((half) * 128 + sr0) * K + ((kt) * 64 + sc0), (ldsh) + o0); \
    gload_lds16((gbase) + (long)((half) * 128 + sr1) * K + ((kt) * 64 + sc1), (ldsh) + o1); \
} while (0)

    f32x4 acc[8][4];
#pragma unroll
    for (int i = 0; i < 8; ++i)
#pragma unroll
        for (int j = 0; j < 4; ++j)
            acc[i][j] = (f32x4){0.f, 0.f, 0.f, 0.f};

    // P_LO(ks): read all 4 B-frags (both halves) + 4 A-h0 frags at K-step ks,
    //           then 16 MFMA into acc rows 0-3 (A-half 0).
    // P_HI(ks): read 4 A-h1 frags, REUSE bv_ registers, 16 MFMA rows 4-7.
    // 24 ds_read_b128 per K-tile(64) for 64 MFMA = 0.375 reads/MFMA.
#define PHASE_LO(ks, ...) do {                                                        \
    bf16x8 af_[4];                                                                    \
    _Pragma("unroll")                                                                 \
    for (int i_ = 0; i_ < 4; ++i_)                                                    \
        af_[i_] = *(const bf16x8*)(ldsA +                                             \
                      ((wm * 4 + i_) * 2 + (ks)) * 1024 + rbase);                     \
    _Pragma("unroll")                                                                 \
    for (int c_ = 0; c_ < 4; ++c_)                                                    \
        bv_[c_] = *(const bf16x8*)(ldsB + (c_ >> 1) * 16384 +                         \
                      ((wn * 2 + (c_ & 1)) * 2 + (ks)) * 1024 + rbase);               \
    __VA_ARGS__;                                                                      \
    asm volatile("s_barrier" ::: "memory");                                           \
    asm volatile("s_waitcnt lgkmcnt(0)" ::: "memory");                                \
    __builtin_amdgcn_s_setprio(1);                                                    \
    _Pragma("unroll")                                                                 \
    for (int i_ = 0; i_ < 4; ++i_)                                                    \
        _Pragma("unroll")                                                             \
        for (int c_ = 0; c_ < 4; ++c_)                                                \
            acc[i_][c_] = __builtin_amdgcn_mfma_f32_16x16x32_bf16(                    \
                af_[i_], bv_[c_], acc[i_][c_], 0, 0, 0);                              \
    __builtin_amdgcn_s_setprio(0);                                                    \
} while (0)

#define PHASE_HI(ks, ...) do {                                                        \
    bf16x8 af_[4];                                                                    \
    _Pragma("unroll")                                                                 \
    for (int i_ = 0; i_ < 4; ++i_)                                                    \
        af_[i_] = *(const bf16x8*)(ldsA + 16384 +                                     \
                      ((wm * 4 + i_) * 2 + (ks)) * 1024 + rbase);                     \
    __VA_ARGS__;                                                                      \
    asm volatile("s_barrier" ::: "memory");                                           \
    asm volatile("s_waitcnt lgkmcnt(0)" ::: "memory");                                \
    __builtin_amdgcn_s_setprio(1);                                                    \
    _Pragma("unroll")                                                                 \
    for (int i_ = 0; i_ < 4; ++i_)                                                    \
        _Pragma("unroll")                                                             \
        for (int c_ = 0; c_ < 4; ++c_)                                                \
            acc[4 + i_][c_] = __builtin_amdgcn_mfma_f32_16x16x32_bf16(                \
                af_[i_], bv_[c_], acc[4 + i_][c_], 0, 0, 0);                          \
    __builtin_amdgcn_s_setprio(0);                                                    \
} while (0)

    // -------- prologue: K0 fully + K1 h0s; vmcnt(4) => K0 landed -------------------
    {
        char* a0 = sm;
        char* b0 = sm + 32768;
        char* a1 = sm + 65536;
        char* b1 = sm + 65536 + 32768;
        STAGE_HT(Abase, 0, 0, a0);
        STAGE_HT(Bbase, 0, 0, b0);
        STAGE_HT(Abase, 0, 1, a0 + 16384);
        STAGE_HT(Bbase, 0, 1, b0 + 16384);
        STAGE_HT(Abase, 1, 0, a1);
        STAGE_HT(Bbase, 1, 0, b1);
        asm volatile("s_waitcnt vmcnt(4)" ::: "memory");
        asm volatile("s_barrier" ::: "memory");
    }

    const int NT = K / 64;
    for (int t = 0; t < NT; ++t) {
        const int buf = t & 1;
        char* ldsA  = sm + buf * 65536;
        char* ldsB  = ldsA + 32768;
        char* ldsAn = sm + (buf ^ 1) * 65536;
        char* ldsBn = ldsAn + 32768;
        bf16x8 bv_[4];

        // P0: ks=0 rows 0-3; stage tile t+1's h1 halves into the idle buffer
        PHASE_LO(0,
              if (t + 1 < NT) {
                  STAGE_HT(Abase, t + 1, 1, ldsAn + 16384);
                  STAGE_HT(Bbase, t + 1, 1, ldsBn + 16384);
              });
        asm volatile("s_barrier" ::: "memory");

        // P1: ks=0 rows 4-7 (B reused in regs)
        PHASE_HI(0, );
        asm volatile("s_barrier" ::: "memory");

        // P2: ks=1 rows 0-3 (last LDS reads of A-h0 and both B halves)
        PHASE_LO(1, );
        asm volatile("s_barrier" ::: "memory");

        // P3: ks=1 rows 4-7; stage t+2 h0s into current buffer (A-h0/B-h0 freed
        // by P2's barrier); counted wait covers all of tile t+1.
        PHASE_HI(1,
              if (t + 2 < NT) {
                  STAGE_HT(Abase, t + 2, 0, ldsA);
                  STAGE_HT(Bbase, t + 2, 0, ldsB);
              });
        if (t + 2 < NT) { asm volatile("s_waitcnt vmcnt(4)" ::: "memory"); }
        else            { asm volatile("s_waitcnt vmcnt(0)" ::: "memory"); }
        asm volatile("s_barrier" ::: "memory");
    }

    // -------- epilogue: C/D layout col=lane&15, row=(lane>>4)*4+reg ----------------
    const int erow = (lane >> 4) * 4;
    const int ecol = lane & 15;
#pragma unroll
    for (int a = 0; a < 8; ++a)
#pragma unroll
        for (int c = 0; c < 4; ++c)
#pragma unroll
            for (int r = 0; r < 4; ++r) {
                long row = trow0 + (a >> 2) * 128 + wm * 64 + (a & 3) * 16 + erow + r;
                long col = tcol0 + (c >> 1) * 128 + wn * 32 + (c & 1) * 16 + ecol;
                C[row * N + col] = acc[a][c][r] * scale;
            }
#undef PHASE_LO
#undef PHASE_HI
#undef STAGE_HT
}

// -----------------------------------------------------------------------------------
extern "C" void kernel_launch(void* const* d_in, const int* in_sizes, int n_in,
                              void* d_out, int out_size, void* d_ws, size_t ws_size,
                              hipStream_t stream) {
    const int*   x    = (const int*)d_in[0];
    const float* emb  = (const float*)d_in[1];
    const float* wq   = (const float*)d_in[2];
    const float* wk   = (const float*)d_in[3];
    const float* wv   = (const float*)d_in[4];
    const float* wo   = (const float*)d_in[5];
    const float* wout = (const float*)d_in[6];
    float* logits = (float*)d_out;

    char* ws = (char*)d_ws;
    size_t off = 0;
    auto alloc = [&](size_t bytes) {
        char* p = ws + off;
        off += (bytes + 255) & ~(size_t)255;
        return p;
    };
    bf16_t* hb    = (bf16_t*)alloc((size_t)BT * DIM * 2);
    bf16_t* qb    = (bf16_t*)alloc((size_t)BT * DIM * 2);
    bf16_t* kb    = (bf16_t*)alloc((size_t)BT * DIM * 2);
    bf16_t* vtb   = (bf16_t*)alloc((size_t)BATCH * DIM * SEQ * 2);
    bf16_t* attnb = (bf16_t*)alloc((size_t)BATCH * SEQ * SEQ * 2);
    bf16_t* o1b   = (bf16_t*)alloc((size_t)BT * DIM * 2);
    bf16_t* o2b   = (bf16_t*)alloc((size_t)BT * DIM * 2);
    bf16_t* wqb   = (bf16_t*)alloc((size_t)DIM * DIM * 2);
    bf16_t* wkb   = (bf16_t*)alloc((size_t)DIM * DIM * 2);
    bf16_t* wvb   = (bf16_t*)alloc((size_t)DIM * DIM * 2);
    bf16_t* wob   = (bf16_t*)alloc((size_t)DIM * DIM * 2);
    bf16_t* woutb = (bf16_t*)alloc((size_t)VOCAB * DIM * 2);

    {
        int n4 = DIM * DIM / 4;
        cast_f32_to_bf16<<<n4 / 256, 256, 0, stream>>>(wq, wqb, n4);
        cast_f32_to_bf16<<<n4 / 256, 256, 0, stream>>>(wk, wkb, n4);
        cast_f32_to_bf16<<<n4 / 256, 256, 0, stream>>>(wv, wvb, n4);
        cast_f32_to_bf16<<<n4 / 256, 256, 0, stream>>>(wo, wob, n4);
        int n4o = VOCAB * DIM / 4;
        cast_f32_to_bf16<<<n4o / 256, 256, 0, stream>>>(wout, woutb, n4o);
    }

    embed_gather<<<BT, 256, 0, stream>>>(x, emb, hb);

    dim3 blk(256);
    gemm_bt<0, bf16_t><<<dim3(DIM / 128, BT / 128, 1), blk, 0, stream>>>(
        hb, wqb, qb, BT, DIM, DIM, 0, 0, 0, 0.01f);
    gemm_bt<0, bf16_t><<<dim3(DIM / 128, BT / 128, 1), blk, 0, stream>>>(
        hb, wkb, kb, BT, DIM, DIM, 0, 0, 0, 0.01f);
    gemm_bt<0, bf16_t><<<dim3(SEQ / 128, DIM / 128, BATCH), blk, 0, stream>>>(
        wvb, hb, vtb, DIM, SEQ, DIM, 0, (long)SEQ * DIM, (long)DIM * SEQ, 0.1f);
    gemm_bt<1, bf16_t><<<dim3(SEQ / 128, SEQ / 128, BATCH), blk, 0, stream>>>(
        qb, kb, attnb, SEQ, SEQ, DIM,
        (long)SEQ * DIM, (long)SEQ * DIM, (long)SEQ * SEQ, 0.01f);
    gemm_bt<0, bf16_t><<<dim3(DIM / 128, SEQ / 128, BATCH), blk, 0, stream>>>(
        attnb, vtb, o1b, SEQ, DIM, SEQ,
        (long)SEQ * SEQ, (long)DIM * SEQ, (long)SEQ * DIM, 0.01f);
    gemm_bt<0, bf16_t><<<dim3(DIM / 128, BT / 128, 1), blk, 0, stream>>>(
        o1b, wob, o2b, BT, DIM, DIM, 0, 0, 0, 0.1f);

    // logits: 256x256 pipelined; grid 1-D = 32 * 125 = 4000 blocks x 512 threads
    gemm_bt_256<<<(BT / 256) * (VOCAB / 256), 512, 0, stream>>>(
        o2b, woutb, logits, VOCAB, DIM, 1.0f);
}

// Round 8
// 937.416 us; speedup vs baseline: 1.3550x; 1.0327x over previous
//
#include <hip/hip_runtime.h>

// FHETinyGPT forward: emb-gather -> q/k/v proj -> QK^T+poly-act -> PV -> wo -> logits.
// Small/medium matmuls: m97-structure gemm_bt (128x128, BK=32, 4 waves).
// Logits GEMM: 256x256 8-wave pipelined kernel. R7 established 0.375 reads/MFMA
// (24 ds_read_b128 / 64 MFMA per K-tile). R8 de-serializes the phase interior:
//   - no forced lgkmcnt(0): plain-load ds_reads get compiler fine-grained waits,
//     so MFMA starts when ITS fragments land (overlaps remaining reads).
//   - ONE barrier per phase (end only; was 2). Region safety: each stage target
//     was last read in the PREVIOUS phase; those reads complete before that
//     phase's end barrier (first-use waits + sched_barrier pin).
//   - sched_barrier(0) before each phase-end s_barrier pins the MFMA cluster
//     (and its lgkm waits) so no read is in flight when another wave's
//     gload_lds lands in the same region.
// Staging plan unchanged from R4/R7 (verified): P0 stages t+1-h1 (idle buf);
// P3 stages t+2-h0 (current buf, freed by P2); tile-end vmcnt(4) => t+1 landed.

typedef __bf16 bf16_t;
typedef __bf16 bf16x8 __attribute__((ext_vector_type(8)));
typedef __bf16 bf16x4 __attribute__((ext_vector_type(4)));
typedef float  f32x4  __attribute__((ext_vector_type(4)));

#define VOCAB 32000
#define DIM   1024
#define BATCH 4
#define SEQ   2048
#define BT    (BATCH*SEQ)   // 8192

__device__ __forceinline__ void gload_lds16(const void* g, void* l) {
    __builtin_amdgcn_global_load_lds(
        (const __attribute__((address_space(1))) void*)g,
        (__attribute__((address_space(3))) void*)l,
        16, 0, 0);
}

// ---------------- weight cast f32 -> bf16 ------------------------------------------
__global__ void cast_f32_to_bf16(const float* __restrict__ in, bf16_t* __restrict__ out, int n4) {
    int i = blockIdx.x * blockDim.x + threadIdx.x;
    if (i < n4) {
        float4 v = ((const float4*)in)[i];
        bf16x4 o;
        o.x = (bf16_t)v.x; o.y = (bf16_t)v.y; o.z = (bf16_t)v.z; o.w = (bf16_t)v.w;
        ((bf16x4*)out)[i] = o;
    }
}

// ---------------- h = emb_w[x] * 0.01 -> bf16 [BT, DIM] ----------------------------
__global__ void embed_gather(const int* __restrict__ x, const float* __restrict__ emb,
                             bf16_t* __restrict__ h) {
    const int tok = blockIdx.x;
    const int row = x[tok];
    const float4* src = (const float4*)(emb + (long)row * DIM);
    bf16x4* dst = (bf16x4*)(h + (long)tok * DIM);
    int j = threadIdx.x;
    float4 v = src[j];
    bf16x4 o;
    o.x = (bf16_t)(v.x * 0.01f); o.y = (bf16_t)(v.y * 0.01f);
    o.z = (bf16_t)(v.z * 0.01f); o.w = (bf16_t)(v.w * 0.01f);
    dst[j] = o;
}

// ---------------- gemm_bt (m97-structure, for the small/medium matmuls) ------------
template<int ACT, typename CT>
__global__ __launch_bounds__(256) void gemm_bt(
    const bf16_t* __restrict__ A, const bf16_t* __restrict__ B, CT* __restrict__ C,
    int M, int N, int K, long sA, long sB, long sC, float scale)
{
    __shared__ __align__(16) bf16_t lsA[128 * 32];
    __shared__ __align__(16) bf16_t lsB[128 * 32];

    const int bz = blockIdx.z;
    A += (long)bz * sA;  B += (long)bz * sB;  C += (long)bz * sC;

    const int tm = blockIdx.y, tn = blockIdx.x;
    const int t = threadIdx.x;
    const int lane = t & 63, wave = t >> 6;
    const int wm = (wave >> 1) * 64;
    const int wn = (wave & 1) * 64;

    const int srow = t >> 2;
    const int scol = (t & 3) * 8;
    const bf16_t* gA = A + (long)(tm * 128 + srow) * K + scol;
    const bf16_t* gB = B + (long)(tn * 128 + srow) * K + scol;
    bf16_t* lA = &lsA[srow * 32 + scol];
    bf16_t* lB = &lsB[srow * 32 + scol];

    f32x4 acc[4][4];
#pragma unroll
    for (int i = 0; i < 4; ++i)
#pragma unroll
        for (int j = 0; j < 4; ++j)
            acc[i][j] = (f32x4){0.f, 0.f, 0.f, 0.f};

    const int arow = lane & 15;
    const int acol = (lane >> 4) * 8;

    for (int k0 = 0; k0 < K; k0 += 32) {
        __syncthreads();
        gload_lds16(gA + k0,                lA);
        gload_lds16(gA + k0 + 64 * (long)K, lA + 64 * 32);
        gload_lds16(gB + k0,                lB);
        gload_lds16(gB + k0 + 64 * (long)K, lB + 64 * 32);
        __syncthreads();

        bf16x8 af[4], bfr[4];
#pragma unroll
        for (int i = 0; i < 4; ++i) {
            af[i]  = *(const bf16x8*)&lsA[(wm + i * 16 + arow) * 32 + acol];
            bfr[i] = *(const bf16x8*)&lsB[(wn + i * 16 + arow) * 32 + acol];
        }
#pragma unroll
        for (int i = 0; i < 4; ++i)
#pragma unroll
            for (int j = 0; j < 4; ++j)
                acc[i][j] = __builtin_amdgcn_mfma_f32_16x16x32_bf16(af[i], bfr[j], acc[i][j], 0, 0, 0);
    }

    const int crow0 = tm * 128 + wm + (lane >> 4) * 4;
    const int ccol0 = tn * 128 + wn + (lane & 15);
#pragma unroll
    for (int i = 0; i < 4; ++i)
#pragma unroll
        for (int j = 0; j < 4; ++j)
#pragma unroll
            for (int r = 0; r < 4; ++r) {
                float s = acc[i][j][r] * scale;
                if (ACT) s = s * s * 0.1f + s * 0.1f;
                C[(long)(crow0 + i * 16 + r) * N + (ccol0 + j * 16)] = (CT)s;
            }
}

// ---------------- 256x256 pipelined GEMM: C[M,N] = scale * A[M,K] @ B[N,K]^T -------
// Requires: M == 8192 (32 M-tiles, band swizzle), N % 256 == 0, K % 128 == 0.
// Grid: 1-D, (M/256)*(N/256) blocks of 512 threads.
__global__ __launch_bounds__(512, 2) void gemm_bt_256(
    const bf16_t* __restrict__ A, const bf16_t* __restrict__ B, float* __restrict__ C,
    int N, int K, float scale)
{
    __shared__ __align__(16) char smem[131072];   // 2buf x (A 32KB + B 32KB)
    char* const sm = smem;

    // band swizzle: XCD k owns tm in [4k, 4k+4); tm-inner-4, tn-outer.
    const int lin = blockIdx.x;
    const int xcd = lin & 7, jj = lin >> 3;
    const int tm = xcd * 4 + (jj & 3);
    const int tn = jj >> 2;
    const long trow0 = (long)tm * 256, tcol0 = (long)tn * 256;

    const int tid  = threadIdx.x;
    const int lane = tid & 63;
    const int wave = tid >> 6;
    const int wm = wave >> 2;            // 0..1  (M sub-band within each 128-half)
    const int wn = wave & 3;             // 0..3
    const int lr = lane & 15;
    const int ko2 = (lane >> 4) * 16;    // byte offset of this lane's 16B k-chunk
    // swizzled per-thread byte offset within a 1KB subtile (involution on bits 4-5)
    const int rbase = lr * 64 + (ko2 ^ (((lr >> 1) & 3) << 4));

    // staging decode (R4-verified): physical slot o holds logical slot sigma(o)
    const int o0 = tid * 16, o1 = 8192 + tid * 16;
    int sr0, sc0, sr1, sc1;
    {
        int ol = o0 ^ (((o0 >> 7) & 3) << 4);
        sr0 = ((ol >> 10) >> 1) * 16 + ((ol >> 6) & 15);
        sc0 = ((ol >> 10) & 1) * 32 + ((ol & 63) >> 1);
        ol = o1 ^ (((o1 >> 7) & 3) << 4);
        sr1 = ((ol >> 10) >> 1) * 16 + ((ol >> 6) & 15);
        sc1 = ((ol >> 10) & 1) * 32 + ((ol & 63) >> 1);
    }

    const bf16_t* Abase = A + trow0 * K;
    const bf16_t* Bbase = B + tcol0 * K;

    // stage one half-tile (128 rows x 64 cols) of K-tile kt into LDS half at ldsh
#define STAGE_HT(gbase, kt, half, ldsh) do {                                          \
    gload_lds16((gbase) + (long)((half) * 128 + sr0) * K + ((kt) * 64 + sc0), (ldsh) + o0); \
    gload_lds16((gbase) + (long)((half) * 128 + sr1) * K + ((kt) * 64 + sc1), (ldsh) + o1); \
} while (0)

    f32x4 acc[8][4];
#pragma unroll
    for (int i = 0; i < 8; ++i)
#pragma unroll
        for (int j = 0; j < 4; ++j)
            acc[i][j] = (f32x4){0.f, 0.f, 0.f, 0.f};

    // P_LO(ks): read A-h0 frags + all 4 B-frags at K-step ks (first-use order),
    //           16 MFMA rows 0-3. P_HI(ks): read A-h1 frags, reuse bv_ regs,
    //           16 MFMA rows 4-7. Compiler emits fine-grained lgkmcnt per MFMA;
    //           sched_barrier(0) pins the cluster before the phase-end barrier.
#define PHASE_LO(ks, ...) do {                                                        \
    bf16x8 af_[4];                                                                    \
    af_[0] = *(const bf16x8*)(ldsA + ((wm * 4 + 0) * 2 + (ks)) * 1024 + rbase);       \
    _Pragma("unroll")                                                                 \
    for (int c_ = 0; c_ < 4; ++c_)                                                    \
        bv_[c_] = *(const bf16x8*)(ldsB + (c_ >> 1) * 16384 +                         \
                      ((wn * 2 + (c_ & 1)) * 2 + (ks)) * 1024 + rbase);               \
    _Pragma("unroll")                                                                 \
    for (int i_ = 1; i_ < 4; ++i_)                                                    \
        af_[i_] = *(const bf16x8*)(ldsA +                                             \
                      ((wm * 4 + i_) * 2 + (ks)) * 1024 + rbase);                     \
    __VA_ARGS__;                                                                      \
    __builtin_amdgcn_s_setprio(1);                                                    \
    _Pragma("unroll")                                                                 \
    for (int i_ = 0; i_ < 4; ++i_)                                                    \
        _Pragma("unroll")                                                             \
        for (int c_ = 0; c_ < 4; ++c_)                                                \
            acc[i_][c_] = __builtin_amdgcn_mfma_f32_16x16x32_bf16(                    \
                af_[i_], bv_[c_], acc[i_][c_], 0, 0, 0);                              \
    __builtin_amdgcn_s_setprio(0);                                                    \
    __builtin_amdgcn_sched_barrier(0);                                                \
    asm volatile("s_barrier" ::: "memory");                                           \
} while (0)

#define PHASE_HI(ks, ...) do {                                                        \
    bf16x8 af_[4];                                                                    \
    _Pragma("unroll")                                                                 \
    for (int i_ = 0; i_ < 4; ++i_)                                                    \
        af_[i_] = *(const bf16x8*)(ldsA + 16384 +                                     \
                      ((wm * 4 + i_) * 2 + (ks)) * 1024 + rbase);                     \
    __VA_ARGS__;                                                                      \
    __builtin_amdgcn_s_setprio(1);                                                    \
    _Pragma("unroll")                                                                 \
    for (int i_ = 0; i_ < 4; ++i_)                                                    \
        _Pragma("unroll")                                                             \
        for (int c_ = 0; c_ < 4; ++c_)                                                \
            acc[4 + i_][c_] = __builtin_amdgcn_mfma_f32_16x16x32_bf16(                \
                af_[i_], bv_[c_], acc[4 + i_][c_], 0, 0, 0);                          \
    __builtin_amdgcn_s_setprio(0);                                                    \
    __builtin_amdgcn_sched_barrier(0);                                                \
} while (0)

    // -------- prologue: K0 fully + K1 h0s; vmcnt(4) => K0 landed -------------------
    {
        char* a0 = sm;
        char* b0 = sm + 32768;
        char* a1 = sm + 65536;
        char* b1 = sm + 65536 + 32768;
        STAGE_HT(Abase, 0, 0, a0);
        STAGE_HT(Bbase, 0, 0, b0);
        STAGE_HT(Abase, 0, 1, a0 + 16384);
        STAGE_HT(Bbase, 0, 1, b0 + 16384);
        STAGE_HT(Abase, 1, 0, a1);
        STAGE_HT(Bbase, 1, 0, b1);
        asm volatile("s_waitcnt vmcnt(4)" ::: "memory");
        asm volatile("s_barrier" ::: "memory");
    }

    const int NT = K / 64;
    for (int t = 0; t < NT; ++t) {
        const int buf = t & 1;
        char* ldsA  = sm + buf * 65536;
        char* ldsB  = ldsA + 32768;
        char* ldsAn = sm + (buf ^ 1) * 65536;
        char* ldsBn = ldsAn + 32768;
        bf16x8 bv_[4];

        // P0: ks=0 rows 0-3; stage tile t+1's h1 halves into the idle buffer
        PHASE_LO(0,
              if (t + 1 < NT) {
                  STAGE_HT(Abase, t + 1, 1, ldsAn + 16384);
                  STAGE_HT(Bbase, t + 1, 1, ldsBn + 16384);
              });

        // P1: ks=0 rows 4-7 (B reused in regs)
        PHASE_HI(0, );
        asm volatile("s_barrier" ::: "memory");

        // P2: ks=1 rows 0-3 (last LDS reads of A-h0 and both B halves)
        PHASE_LO(1, );

        // P3: ks=1 rows 4-7; stage t+2 h0s into current buffer (freed by P2's
        // end barrier); counted wait covers all of tile t+1.
        PHASE_HI(1,
              if (t + 2 < NT) {
                  STAGE_HT(Abase, t + 2, 0, ldsA);
                  STAGE_HT(Bbase, t + 2, 0, ldsB);
              });
        if (t + 2 < NT) { asm volatile("s_waitcnt vmcnt(4)" ::: "memory"); }
        else            { asm volatile("s_waitcnt vmcnt(0)" ::: "memory"); }
        asm volatile("s_barrier" ::: "memory");
    }

    // -------- epilogue: C/D layout col=lane&15, row=(lane>>4)*4+reg ----------------
    const int erow = (lane >> 4) * 4;
    const int ecol = lane & 15;
#pragma unroll
    for (int a = 0; a < 8; ++a)
#pragma unroll
        for (int c = 0; c < 4; ++c)
#pragma unroll
            for (int r = 0; r < 4; ++r) {
                long row = trow0 + (a >> 2) * 128 + wm * 64 + (a & 3) * 16 + erow + r;
                long col = tcol0 + (c >> 1) * 128 + wn * 32 + (c & 1) * 16 + ecol;
                C[row * N + col] = acc[a][c][r] * scale;
            }
#undef PHASE_LO
#undef PHASE_HI
#undef STAGE_HT
}

// -----------------------------------------------------------------------------------
extern "C" void kernel_launch(void* const* d_in, const int* in_sizes, int n_in,
                              void* d_out, int out_size, void* d_ws, size_t ws_size,
                              hipStream_t stream) {
    const int*   x    = (const int*)d_in[0];
    const float* emb  = (const float*)d_in[1];
    const float* wq   = (const float*)d_in[2];
    const float* wk   = (const float*)d_in[3];
    const float* wv   = (const float*)d_in[4];
    const float* wo   = (const float*)d_in[5];
    const float* wout = (const float*)d_in[6];
    float* logits = (float*)d_out;

    char* ws = (char*)d_ws;
    size_t off = 0;
    auto alloc = [&](size_t bytes) {
        char* p = ws + off;
        off += (bytes + 255) & ~(size_t)255;
        return p;
    };
    bf16_t* hb    = (bf16_t*)alloc((size_t)BT * DIM * 2);
    bf16_t* qb    = (bf16_t*)alloc((size_t)BT * DIM * 2);
    bf16_t* kb    = (bf16_t*)alloc((size_t)BT * DIM * 2);
    bf16_t* vtb   = (bf16_t*)alloc((size_t)BATCH * DIM * SEQ * 2);
    bf16_t* attnb = (bf16_t*)alloc((size_t)BATCH * SEQ * SEQ * 2);
    bf16_t* o1b   = (bf16_t*)alloc((size_t)BT * DIM * 2);
    bf16_t* o2b   = (bf16_t*)alloc((size_t)BT * DIM * 2);
    bf16_t* wqb   = (bf16_t*)alloc((size_t)DIM * DIM * 2);
    bf16_t* wkb   = (bf16_t*)alloc((size_t)DIM * DIM * 2);
    bf16_t* wvb   = (bf16_t*)alloc((size_t)DIM * DIM * 2);
    bf16_t* wob   = (bf16_t*)alloc((size_t)DIM * DIM * 2);
    bf16_t* woutb = (bf16_t*)alloc((size_t)VOCAB * DIM * 2);

    {
        int n4 = DIM * DIM / 4;
        cast_f32_to_bf16<<<n4 / 256, 256, 0, stream>>>(wq, wqb, n4);
        cast_f32_to_bf16<<<n4 / 256, 256, 0, stream>>>(wk, wkb, n4);
        cast_f32_to_bf16<<<n4 / 256, 256, 0, stream>>>(wv, wvb, n4);
        cast_f32_to_bf16<<<n4 / 256, 256, 0, stream>>>(wo, wob, n4);
        int n4o = VOCAB * DIM / 4;
        cast_f32_to_bf16<<<n4o / 256, 256, 0, stream>>>(wout, woutb, n4o);
    }

    embed_gather<<<BT, 256, 0, stream>>>(x, emb, hb);

    dim3 blk(256);
    gemm_bt<0, bf16_t><<<dim3(DIM / 128, BT / 128, 1), blk, 0, stream>>>(
        hb, wqb, qb, BT, DIM, DIM, 0, 0, 0, 0.01f);
    gemm_bt<0, bf16_t><<<dim3(DIM / 128, BT / 128, 1), blk, 0, stream>>>(
        hb, wkb, kb, BT, DIM, DIM, 0, 0, 0, 0.01f);
    gemm_bt<0, bf16_t><<<dim3(SEQ / 128, DIM / 128, BATCH), blk, 0, stream>>>(
        wvb, hb, vtb, DIM, SEQ, DIM, 0, (long)SEQ * DIM, (long)DIM * SEQ, 0.1f);
    gemm_bt<1, bf16_t><<<dim3(SEQ / 128, SEQ / 128, BATCH), blk, 0, stream>>>(
        qb, kb, attnb, SEQ, SEQ, DIM,
        (long)SEQ * DIM, (long)SEQ * DIM, (long)SEQ * SEQ, 0.01f);
    gemm_bt<0, bf16_t><<<dim3(DIM / 128, SEQ / 128, BATCH), blk, 0, stream>>>(
        attnb, vtb, o1b, SEQ, DIM, SEQ,
        (long)SEQ * SEQ, (long)DIM * SEQ, (long)SEQ * DIM, 0.01f);
    gemm_bt<0, bf16_t><<<dim3(DIM / 128, BT / 128, 1), blk, 0, stream>>>(
        o1b, wob, o2b, BT, DIM, DIM, 0, 0, 0, 0.1f);

    // logits: 256x256 pipelined; grid 1-D = 32 * 125 = 4000 blocks x 512 threads
    gemm_bt_256<<<(BT / 256) * (VOCAB / 256), 512, 0, stream>>>(
        o2b, woutb, logits, VOCAB, DIM, 1.0f);
}